// Round 8
// baseline (129.916 us; speedup 1.0000x reference)
//
#include <hip/hip_runtime.h>
#include <stdint.h>

typedef unsigned long long u64;

#define N 8192
#define NW 128            // 64-bit words per mask row
#define MAX_OUT 256
#define MASK_BYTES ((size_t)N * NW * 8)   // 8 MiB

// ws layout:
//   [0, 8MB)    maskT u64[NW][N]  (column-major: maskT[w*N + i])
//   +8MB        order  int[N]     32 KB
//   +32KB       s_s    float[N]   32 KB
//   +64KB       bbox   float4[N] 128 KB
//   +192KB      area   float[N]   32 KB
//   +224KB      nvalid int
// No init needed anywhere (rank is a permutation; maskT garbage only in
// never-consumed positions; nvalid written each launch).

// ========== Kernel 1: fused rank + scatter + nvalid (no atomics, no init) ====
__global__ __launch_bounds__(1024)
void rank_fused_kernel(const float* __restrict__ score, const float* __restrict__ box,
                       int* __restrict__ order, float* __restrict__ s_s,
                       float4* __restrict__ bbox, float* __restrict__ area,
                       int* __restrict__ nvalid) {
    __shared__ uint32_t ksc[N];        // 32 KB: all score bit-patterns
    __shared__ int psum[32][33];       // +1 pad
    __shared__ int vpart[16];
    const int tid = threadIdx.x;

    const float4* s4 = (const float4*)score;
    float4 a = s4[tid * 2], b = s4[tid * 2 + 1];
    ksc[tid * 8 + 0] = __float_as_uint(a.x);
    ksc[tid * 8 + 1] = __float_as_uint(a.y);
    ksc[tid * 8 + 2] = __float_as_uint(a.z);
    ksc[tid * 8 + 3] = __float_as_uint(a.w);
    ksc[tid * 8 + 4] = __float_as_uint(b.x);
    ksc[tid * 8 + 5] = __float_as_uint(b.y);
    ksc[tid * 8 + 6] = __float_as_uint(b.z);
    ksc[tid * 8 + 7] = __float_as_uint(b.w);
    int c = (a.x >= 0.3f) + (a.y >= 0.3f) + (a.z >= 0.3f) + (a.w >= 0.3f)
          + (b.x >= 0.3f) + (b.y >= 0.3f) + (b.z >= 0.3f) + (b.w >= 0.3f);
    for (int off = 32; off; off >>= 1) c += __shfl_down(c, off);
    if ((tid & 63) == 0) vpart[tid >> 6] = c;
    __syncthreads();
    if (blockIdx.x == 0 && tid == 0) {
        int t = 0;
        #pragma unroll
        for (int w = 0; w < 16; ++w) t += vpart[w];
        *nvalid = t;
    }

    const int i_local = tid & 31;
    const int jg = tid >> 5;
    const int ibase = blockIdx.x * 32;
    const uint32_t si = ksc[ibase + i_local];
    const int i = ibase + i_local;
    int cnt = 0;
    const int j0 = jg * 256;
    #pragma unroll 8
    for (int t = 0; t < 256; ++t) {
        const int j = j0 + t;
        const uint32_t sj = ksc[j];
        cnt += (sj > si || (sj == si && j < i)) ? 1 : 0;
    }
    psum[i_local][jg] = cnt;
    __syncthreads();

    if (tid < 32) {
        int r = 0;
        #pragma unroll
        for (int k = 0; k < 32; ++k) r += psum[tid][k];
        const int ii = ibase + tid;
        order[r] = ii;
        s_s[r] = score[ii];
        float4 cb = ((const float4*)box)[ii * 4];   // first 4 of 16: cx,cy,w,h
        float hw = cb.z * 0.5f, hh = cb.w * 0.5f;
        float x0 = cb.x - hw, y0 = cb.y - hh, x1 = cb.x + hw, y1 = cb.y + hh;
        bbox[r] = make_float4(x0, y0, x1, y1);
        area[r] = (x1 - x0) * (y1 - y0);            // replicate ref: area from xyxy
    }
}

// ========== Kernel 2: suppression bitmask, column-major, div-free fast path ==
__global__ __launch_bounds__(256)
void mask_kernel(const float4* __restrict__ bbox, const float* __restrict__ area,
                 const int* __restrict__ nvalid_p, u64* __restrict__ maskT) {
    const int w = blockIdx.x;
    if (w < (int)(blockIdx.y << 2)) return;          // whole block below diagonal
    const int nv = *nvalid_p;
    if ((int)(blockIdx.y * 256) >= nv) return;
    __shared__ float4 jb[64];
    __shared__ float  ja[64];
    if (threadIdx.x < 64) {
        jb[threadIdx.x] = bbox[w * 64 + threadIdx.x];
        ja[threadIdx.x] = area[w * 64 + threadIdx.x];
    }
    __syncthreads();
    const int i = blockIdx.y * 256 + threadIdx.x;
    if (i >= nv) return;
    if (w < (i >> 6)) return;
    float4 aa4 = bbox[i];
    float  aa = area[i];
    u64 bits = 0, fb = 0;
    #pragma unroll 8
    for (int jj = 0; jj < 64; ++jj) {
        float4 b = jb[jj];
        float lx = fmaxf(aa4.x, b.x), ly = fmaxf(aa4.y, b.y);
        float rx = fminf(aa4.z, b.z), ry = fminf(aa4.w, b.w);
        float ww = fmaxf(rx - lx, 0.0f), hh = fmaxf(ry - ly, 0.0f);
        float inter = ww * hh;
        float denom = ((aa + ja[jj]) - inter) + 1e-9f;  // exact ref op order
        float d = fmaf(-0.3f, denom, inter);            // sign decides iou>0.3
        bits |= ((u64)(d > 0.0f)) << jj;
        fb   |= ((u64)(fabsf(d) <= 1e-5f * denom)) << jj;
    }
    if (fb) {   // rare exact-divide fixup (margin 1e-5 >> ulp(0.3f)~3e-8)
        while (fb) {
            int jj = (int)__builtin_ctzll(fb); fb &= fb - 1;
            float4 b = jb[jj];
            float lx = fmaxf(aa4.x, b.x), ly = fmaxf(aa4.y, b.y);
            float rx = fminf(aa4.z, b.z), ry = fminf(aa4.w, b.w);
            float ww = fmaxf(rx - lx, 0.0f), hh = fmaxf(ry - ly, 0.0f);
            float inter = ww * hh;
            float denom = ((aa + ja[jj]) - inter) + 1e-9f;
            float iou = inter / denom;                   // IEEE div, matches np
            bits = (bits & ~(1ull << jj)) | (((u64)(iou > 0.3f)) << jj);
        }
    }
    maskT[(size_t)w * N + i] = bits;                     // coalesced
}

// ========== Kernel 3: serial greedy — 128 rows per step, single pipe =========
// Step t covers blocks w0=2t, w1=2t+1 (rows [128t, 128t+128)).
// Per lane, prefetched during step t-1 (1-step lookahead):
//   cols:  c00=maskT[w0][128t+lane]  c10=maskT[w1][128t+lane]  c11=maskT[w1][128t+64+lane]
//   specs: s00/s01=maskT[2t+2][rows of t]  s10/s11=maskT[2t+3][rows of t]
//   gathers (old kept, kcount through step t-2 at issue): pg*=maskT[w0][kp*], ph*=maskT[w1][kp*]
// Kept at step t-1 enter via carry (spec words masked by km at end of t-1) —
// exactly 1 generation needed with 1-step lookahead.
// In-step: low-block resolve via ballot(c00); kept l folds into rw1 via
// 2-readlane broadcast of c10; high-block resolve via ballot(c11).
// All loaded words are upper-triangle (written); garbage only reaches
// provably-dead bit positions (validm / keepm / kept-validity arguments).
// Register note (R2/R6 lesson): single pipe, no rotating reference sets.

__device__ __forceinline__ unsigned or_dpp32(unsigned v) {
    v |= (unsigned)__builtin_amdgcn_update_dpp(0, (int)v, 0x111, 0xf, 0xf, true); // row_shr:1
    v |= (unsigned)__builtin_amdgcn_update_dpp(0, (int)v, 0x112, 0xf, 0xf, true); // row_shr:2
    v |= (unsigned)__builtin_amdgcn_update_dpp(0, (int)v, 0x114, 0xf, 0xf, true); // row_shr:4
    v |= (unsigned)__builtin_amdgcn_update_dpp(0, (int)v, 0x118, 0xf, 0xf, true); // row_shr:8
    v |= (unsigned)__builtin_amdgcn_update_dpp(0, (int)v, 0x142, 0xf, 0xf, true); // row_bcast:15
    v |= (unsigned)__builtin_amdgcn_update_dpp(0, (int)v, 0x143, 0xf, 0xf, true); // row_bcast:31
    return v;
}

__device__ __forceinline__ u64 wave_or64(u64 v) {
    unsigned lo = or_dpp32((unsigned)v);
    unsigned hi = or_dpp32((unsigned)(v >> 32));
    unsigned slo = (unsigned)__builtin_amdgcn_readlane((int)lo, 63);
    unsigned shi = (unsigned)__builtin_amdgcn_readlane((int)hi, 63);
    return ((u64)shi << 32) | (u64)slo;
}

#define RL64(v, l) ( ((u64)(unsigned)__builtin_amdgcn_readlane((int)(unsigned)((v) >> 32), (l)) << 32) \
                   |  (u64)(unsigned)__builtin_amdgcn_readlane((int)(unsigned)(v), (l)) )

__global__ __launch_bounds__(64)
void nms_kernel(const u64* __restrict__ maskT, const float* __restrict__ s_s,
                const int* __restrict__ order, const float* __restrict__ box,
                const int* __restrict__ nvalid_p, float* __restrict__ out) {
    const int lane = threadIdx.x;
    const int nv = *nvalid_p;
    const int nblk = (nv + 63) >> 6;
    const int nst = (nblk + 1) >> 1;
    int kcount = 0;
    int kp0 = 0, kp1 = 0, kp2 = 0, kp3 = 0;   // kept idx slots lane, 64+l, 128+l, 192+l
    u64 carry0 = 0, carry1 = 0;

    // in-flight pipe (primed for step 0)
    u64 pc00 = 0, pc10 = 0, pc11 = 0;
    u64 ps00 = 0, ps01 = 0, ps10 = 0, ps11 = 0;
    u64 pg0=0, pg1=0, pg2=0, pg3=0, ph0=0, ph1=0, ph2=0, ph3=0;

    if (nst > 0) {
        pc00 = maskT[lane];
        if (1 < nblk) {
            pc10 = maskT[(size_t)1 * N + lane];
            pc11 = maskT[(size_t)1 * N + 64 + lane];
        }
        if (2 < nblk) {
            ps00 = maskT[(size_t)2 * N + lane];
            ps01 = maskT[(size_t)2 * N + 64 + lane];
        }
        if (3 < nblk) {
            ps10 = maskT[(size_t)3 * N + lane];
            ps11 = maskT[(size_t)3 * N + 64 + lane];
        }
    }

    for (int t = 0; t < nst && kcount < MAX_OUT; ++t) {
        // ---- consume pipe into locals
        u64 c00 = pc00, c10 = pc10, c11 = pc11;
        u64 x0 = pg0 | pg1 | pg2 | pg3 | carry0;
        u64 x1 = ph0 | ph1 | ph2 | ph3 | carry1;
        u64 s00 = ps00, s01 = ps01, s10 = ps10, s11 = ps11;

        // ---- reissue pipe for step t+1 (loads fly under this step's compute)
        pc00 = pc10 = pc11 = 0;
        ps00 = ps01 = ps10 = ps11 = 0;
        pg0 = pg1 = pg2 = pg3 = ph0 = ph1 = ph2 = ph3 = 0;
        const int t1 = t + 1;
        if (t1 < nst) {
            const int w0n = t1 << 1, w1n = w0n | 1;
            const size_t r0n = ((size_t)t1 << 7) + lane;
            const u64* cw0 = maskT + (size_t)w0n * N;
            const int kc = kcount;                 // kept through step t-1
            pc00 = cw0[r0n];
            if (lane < kc)        pg0 = cw0[kp0];
            if (lane +  64 < kc)  pg1 = cw0[kp1];
            if (lane + 128 < kc)  pg2 = cw0[kp2];
            if (lane + 192 < kc)  pg3 = cw0[kp3];
            if (w1n < nblk) {
                const u64* cw1 = maskT + (size_t)w1n * N;
                pc10 = cw1[r0n];
                pc11 = cw1[r0n + 64];
                if (lane < kc)        ph0 = cw1[kp0];
                if (lane +  64 < kc)  ph1 = cw1[kp1];
                if (lane + 128 < kc)  ph2 = cw1[kp2];
                if (lane + 192 < kc)  ph3 = cw1[kp3];
            }
            const int ws0 = w0n + 2, ws1 = w0n + 3;
            if (ws0 < nblk) {
                const u64* sw0 = maskT + (size_t)ws0 * N;
                ps00 = sw0[r0n];
                ps01 = sw0[r0n + 64];
            }
            if (ws1 < nblk) {
                const u64* sw1 = maskT + (size_t)ws1 * N;
                ps10 = sw1[r0n];
                ps11 = sw1[r0n + 64];
            }
        }

        // ---- suppression words: two independent DPP reduces (interleave)
        u64 rw0 = wave_or64(x0);
        u64 rw1 = wave_or64(x1);

        const int base = t << 7;
        const int rem0 = nv - base;                 // >= 1 while t < nst
        const int rem1 = rem0 - 64;
        u64 vm0 = (rem0 >= 64) ? ~0ull : ((1ull << rem0) - 1ull);
        u64 vm1 = (rem1 >= 64) ? ~0ull : ((rem1 > 0) ? ((1ull << rem1) - 1ull) : 0ull);

        u64 km0 = 0, km1 = 0;
        u64 todo = vm0 & ~rw0;
        while (todo) {
            int l = (int)__builtin_ctzll(todo);
            u64 row_l = __ballot(((c00 >> l) & 1ull) != 0);  // in-block via symmetry
            const int pos = base + l;
            const bool own = (lane == (kcount & 63));
            const int slot = kcount >> 6;                    // uniform
            kp0 = (own && slot == 0) ? pos : kp0;
            kp1 = (own && slot == 1) ? pos : kp1;
            kp2 = (own && slot == 2) ? pos : kp2;
            kp3 = (own && slot == 3) ? pos : kp3;
            km0 |= 1ull << l;
            kcount++;
            // diagonal bit of row_l not guaranteed for degenerate tiny boxes
            todo &= ~(row_l | (1ull << l));
            rw1 |= RL64(c10, l);        // kept l suppresses high-block candidates
            if (kcount >= MAX_OUT) break;
        }
        if (kcount < MAX_OUT) {
            todo = vm1 & ~rw1;
            while (todo) {
                int l = (int)__builtin_ctzll(todo);
                u64 row_l = __ballot(((c11 >> l) & 1ull) != 0);
                const int pos = base + 64 + l;
                const bool own = (lane == (kcount & 63));
                const int slot = kcount >> 6;
                kp0 = (own && slot == 0) ? pos : kp0;
                kp1 = (own && slot == 1) ? pos : kp1;
                kp2 = (own && slot == 2) ? pos : kp2;
                kp3 = (own && slot == 3) ? pos : kp3;
                km1 |= 1ull << l;
                kcount++;
                todo &= ~(row_l | (1ull << l));
                if (kcount >= MAX_OUT) break;
            }
        }
        // ---- carry: this step's kept × spec words (for step t+1)
        u64 keepm0 = ((km0 >> lane) & 1ull) ? ~0ull : 0ull;
        u64 keepm1 = ((km1 >> lane) & 1ull) ? ~0ull : 0ull;
        carry0 = (s00 & keepm0) | (s01 & keepm1);
        carry1 = (s10 & keepm0) | (s11 & keepm1);
    }

    // outputs: [score 256][box 256*16][valid 256], all float32
    float* out_score = out;
    float* out_box   = out + MAX_OUT;
    float* out_valid = out + MAX_OUT + MAX_OUT * 16;
    const float4* box4 = (const float4*)box;
    float4* ob4 = (float4*)out_box;
    #define EMIT_SLOT(Q, KP) do {                                              \
        const int t = lane + 64 * (Q);                                         \
        if (t < kcount) {                                                      \
            int p = (KP);                                                      \
            out_score[t] = s_s[p];                                             \
            out_valid[t] = 1.0f;                                               \
            int oi = order[p];                                                 \
            _Pragma("unroll")                                                  \
            for (int q = 0; q < 4; ++q) ob4[t * 4 + q] = box4[oi * 4 + q];     \
        } else {                                                               \
            out_score[t] = 0.0f;                                               \
            out_valid[t] = 0.0f;                                               \
            float4 z = make_float4(0.f, 0.f, 0.f, 0.f);                        \
            _Pragma("unroll")                                                  \
            for (int q = 0; q < 4; ++q) ob4[t * 4 + q] = z;                    \
        }                                                                      \
    } while (0)
    EMIT_SLOT(0, kp0);
    EMIT_SLOT(1, kp1);
    EMIT_SLOT(2, kp2);
    EMIT_SLOT(3, kp3);
    #undef EMIT_SLOT
}

extern "C" void kernel_launch(void* const* d_in, const int* in_sizes, int n_in,
                              void* d_out, int out_size, void* d_ws, size_t ws_size,
                              hipStream_t stream) {
    const float* score = (const float*)d_in[0];   // (8192,1) f32
    const float* box   = (const float*)d_in[1];   // (8192,16) f32
    char* ws = (char*)d_ws;
    u64*    maskT  = (u64*)ws;
    int*    order  = (int*)   (ws + MASK_BYTES);
    float*  s_s    = (float*) (ws + MASK_BYTES + 32768);
    float4* bbox   = (float4*)(ws + MASK_BYTES + 65536);
    float*  area   = (float*) (ws + MASK_BYTES + 65536 + 131072);
    int*    nvalid = (int*)   (ws + MASK_BYTES + 65536 + 131072 + 32768);

    rank_fused_kernel<<<256, 1024, 0, stream>>>(score, box, order, s_s, bbox, area, nvalid);
    mask_kernel<<<dim3(128, 32), 256, 0, stream>>>(bbox, area, nvalid, maskT);
    nms_kernel<<<1, 64, 0, stream>>>(maskT, s_s, order, box, nvalid, (float*)d_out);
}